// Round 1
// baseline (1165.123 us; speedup 1.0000x reference)
//
#include <hip/hip_runtime.h>
#include <hip/hip_bf16.h>

// ---------------------------------------------------------------------------
// GNN encoder: SAGEConv -> BN -> 2x (GINConv -> BN), concat outputs + add-pool
// N=100000, E=1600000, F=D=128, L=3, G=500
// ---------------------------------------------------------------------------

#define BN_EPS 1e-5f

// ---------------- CSR build ----------------

__global__ void k_count(const int* __restrict__ dst, int E, int* __restrict__ cnt) {
    int e = blockIdx.x * 256 + threadIdx.x;
    if (e < E) atomicAdd(&cnt[dst[e]], 1);
}

__global__ void k_scan_a(const int* __restrict__ deg, int N, int* __restrict__ bsum) {
    __shared__ int sm[256];
    int base = blockIdx.x * 1024;
    int s = 0;
#pragma unroll
    for (int t = 0; t < 4; t++) {
        int i = base + threadIdx.x + t * 256;
        if (i < N) s += deg[i];
    }
    sm[threadIdx.x] = s;
    __syncthreads();
    for (int off = 128; off > 0; off >>= 1) {
        if (threadIdx.x < off) sm[threadIdx.x] += sm[threadIdx.x + off];
        __syncthreads();
    }
    if (threadIdx.x == 0) bsum[blockIdx.x] = sm[0];
}

__global__ void k_scan_b(const int* __restrict__ bsum, int nb, int* __restrict__ bbase) {
    if (threadIdx.x == 0) {
        int run = 0;
        for (int i = 0; i < nb; i++) { bbase[i] = run; run += bsum[i]; }
    }
}

// in-place: deg_cursor holds degree counts on entry, running positions on exit
__global__ void k_scan_c(int* __restrict__ deg_cursor, int N,
                         const int* __restrict__ bbase, int* __restrict__ rp, int E) {
    __shared__ int sm[256];
    int base = blockIdx.x * 1024 + threadIdx.x * 4;
    int v[4];
    int s = 0;
#pragma unroll
    for (int t = 0; t < 4; t++) {
        int i = base + t;
        v[t] = (i < N) ? deg_cursor[i] : 0;
        s += v[t];
    }
    sm[threadIdx.x] = s;
    __syncthreads();
    // inclusive Hillis-Steele over 256 thread sums
    for (int off = 1; off < 256; off <<= 1) {
        int y = (threadIdx.x >= off) ? sm[threadIdx.x - off] : 0;
        __syncthreads();
        sm[threadIdx.x] += y;
        __syncthreads();
    }
    int excl = sm[threadIdx.x] - s;
    int b = bbase[blockIdx.x] + excl;
#pragma unroll
    for (int t = 0; t < 4; t++) {
        int i = base + t;
        if (i < N) { rp[i] = b; deg_cursor[i] = b; b += v[t]; }
    }
    if (blockIdx.x == 0 && threadIdx.x == 0) rp[N] = E;
}

__global__ void k_fill(const int* __restrict__ src, const int* __restrict__ dst, int E,
                       int* __restrict__ cursor, int* __restrict__ csr) {
    int e = blockIdx.x * 256 + threadIdx.x;
    if (e < E) {
        int pos = atomicAdd(&cursor[dst[e]], 1);
        csr[pos] = src[e];
    }
}

// ---------------- aggregation ----------------
// 8 nodes per 256-thread block, 32 lanes x float4 per node.

__global__ void k_aggr_sage(const int* __restrict__ rp, const int* __restrict__ csr,
                            const float* __restrict__ x, float* __restrict__ out, int N) {
    int node = blockIdx.x * 8 + (threadIdx.x >> 5);
    int f4 = threadIdx.x & 31;
    if (node >= N) return;
    int lo = rp[node], hi = rp[node + 1];
    float4 s = make_float4(0.f, 0.f, 0.f, 0.f);
    for (int j = lo; j < hi; j++) {
        int sn = csr[j];
        float4 v = reinterpret_cast<const float4*>(x + (size_t)sn * 128)[f4];
        s.x += v.x; s.y += v.y; s.z += v.z; s.w += v.w;
    }
    int d = hi - lo;
    float inv = 1.0f / (float)(d > 1 ? d : 1);
    s.x *= inv; s.y *= inv; s.z *= inv; s.w *= inv;
    reinterpret_cast<float4*>(out + (size_t)node * 128)[f4] = s;
}

// GIN: out = h[node] + sum_{nb} h[nb];  h has row stride 384 (lives in node_feats)
__global__ void k_aggr_gin(const int* __restrict__ rp, const int* __restrict__ csr,
                           const float* __restrict__ h, float* __restrict__ out, int N) {
    int node = blockIdx.x * 8 + (threadIdx.x >> 5);
    int f4 = threadIdx.x & 31;
    if (node >= N) return;
    int lo = rp[node], hi = rp[node + 1];
    float4 s = *reinterpret_cast<const float4*>(h + (size_t)node * 384 + f4 * 4);
    for (int j = lo; j < hi; j++) {
        int sn = csr[j];
        float4 v = *reinterpret_cast<const float4*>(h + (size_t)sn * 384 + f4 * 4);
        s.x += v.x; s.y += v.y; s.z += v.z; s.w += v.w;
    }
    reinterpret_cast<float4*>(out + (size_t)node * 128)[f4] = s;
}

// ---------------- GEMM:  C = relu( A1@W1 [+ A2@W2] + bias ) ----------------
// K = 128 per term, Dout = 128. Tile: 64 nodes x 128 cols, 256 threads,
// each thread 8 nodes x 4 cols.

__global__ __launch_bounds__(256) void k_gemm(
    const float* __restrict__ A1, int lda1, const float* __restrict__ W1,
    const float* __restrict__ A2, int lda2, const float* __restrict__ W2,
    const float* __restrict__ bias, float* __restrict__ C, int ldc, int N) {
    __shared__ float As[64 * 128];  // 32 KB
    const int tid = threadIdx.x;
    const int tc = tid & 31;   // col group: cols tc*4 .. tc*4+3
    const int tr = tid >> 5;   // node group: nodes tr*8 .. tr*8+7
    const int n0 = blockIdx.x * 64;

    float acc[8][4];
#pragma unroll
    for (int i = 0; i < 8; i++)
#pragma unroll
        for (int j = 0; j < 4; j++) acc[i][j] = 0.f;

#pragma unroll 1
    for (int term = 0; term < 2; ++term) {
        const float* A = term ? A2 : A1;
        if (!A) break;
        const float* W = term ? W2 : W1;
        const int lda = term ? lda2 : lda1;

        __syncthreads();
        // stage A tile (64 x 128) into LDS
#pragma unroll
        for (int t = 0; t < 8; t++) {
            int idx = tid + t * 256;      // 0..2047 float4 slots
            int row = idx >> 5, f4 = idx & 31;
            float4 v = make_float4(0.f, 0.f, 0.f, 0.f);
            int n = n0 + row;
            if (n < N) v = *reinterpret_cast<const float4*>(A + (size_t)n * lda + f4 * 4);
            *reinterpret_cast<float4*>(As + row * 128 + f4 * 4) = v;
        }
        __syncthreads();

        const float4* W4 = reinterpret_cast<const float4*>(W);
#pragma unroll 4
        for (int k4 = 0; k4 < 32; k4++) {
            float4 w0 = W4[(k4 * 4 + 0) * 32 + tc];
            float4 w1 = W4[(k4 * 4 + 1) * 32 + tc];
            float4 w2 = W4[(k4 * 4 + 2) * 32 + tc];
            float4 w3 = W4[(k4 * 4 + 3) * 32 + tc];
#pragma unroll
            for (int i = 0; i < 8; i++) {
                const float4 a = *reinterpret_cast<const float4*>(&As[(tr * 8 + i) * 128 + k4 * 4]);
#define FMA4(av, wv)                                  \
    acc[i][0] = fmaf(av, wv.x, acc[i][0]);            \
    acc[i][1] = fmaf(av, wv.y, acc[i][1]);            \
    acc[i][2] = fmaf(av, wv.z, acc[i][2]);            \
    acc[i][3] = fmaf(av, wv.w, acc[i][3]);
                FMA4(a.x, w0) FMA4(a.y, w1) FMA4(a.z, w2) FMA4(a.w, w3)
#undef FMA4
            }
        }
    }

    const float4 b4 = reinterpret_cast<const float4*>(bias)[tc];
#pragma unroll
    for (int i = 0; i < 8; i++) {
        int n = n0 + tr * 8 + i;
        if (n < N) {
            float4 o;
            o.x = fmaxf(acc[i][0] + b4.x, 0.f);
            o.y = fmaxf(acc[i][1] + b4.y, 0.f);
            o.z = fmaxf(acc[i][2] + b4.z, 0.f);
            o.w = fmaxf(acc[i][3] + b4.w, 0.f);
            *reinterpret_cast<float4*>(C + (size_t)n * ldc + tc * 4) = o;
        }
    }
}

// ---------------- BatchNorm ----------------

__global__ void k_stats(const float* __restrict__ C, int ld, int N,
                        float* __restrict__ gsum, float* __restrict__ gsq) {
    __shared__ float ls[256], lq[256];
    int d = threadIdx.x & 127;
    int r = threadIdx.x >> 7;
    float s = 0.f, q = 0.f;
    for (int n = blockIdx.x * 2 + r; n < N; n += gridDim.x * 2) {
        float v = C[(size_t)n * ld + d];
        s += v;
        q += v * v;
    }
    ls[threadIdx.x] = s;
    lq[threadIdx.x] = q;
    __syncthreads();
    if (threadIdx.x < 128) {
        s = ls[threadIdx.x] + ls[threadIdx.x + 128];
        q = lq[threadIdx.x] + lq[threadIdx.x + 128];
        unsafeAtomicAdd(&gsum[threadIdx.x], s);
        unsafeAtomicAdd(&gsq[threadIdx.x], q);
    }
}

__global__ void k_bnfin(const float* __restrict__ gsum, const float* __restrict__ gsq,
                        const float* __restrict__ gamma, const float* __restrict__ beta,
                        int N, float* __restrict__ a, float* __restrict__ c) {
    int d = threadIdx.x;  // 128 threads
    float invN = 1.0f / (float)N;
    float mu = gsum[d] * invN;
    float var = gsq[d] * invN - mu * mu;
    float rs = rsqrtf(var + BN_EPS);
    float aa = gamma[d] * rs;
    a[d] = aa;
    c[d] = beta[d] - mu * aa;
}

// normalize: out[n*384 + f] = Cin[n*ldin + f]*a[f] + c[f]   (in-place safe)
__global__ void k_norm(const float* __restrict__ Cin, int ldin,
                       const float* __restrict__ a, const float* __restrict__ c,
                       float* __restrict__ outnf, int N) {
    int idx = blockIdx.x * 256 + threadIdx.x;  // over N*32 float4 slots
    if (idx >= N * 32) return;
    int n = idx >> 5, f4 = idx & 31;
    float4 v = *reinterpret_cast<const float4*>(Cin + (size_t)n * ldin + f4 * 4);
    float4 a4 = reinterpret_cast<const float4*>(a)[f4];
    float4 c4 = reinterpret_cast<const float4*>(c)[f4];
    v.x = fmaf(v.x, a4.x, c4.x);
    v.y = fmaf(v.y, a4.y, c4.y);
    v.z = fmaf(v.z, a4.z, c4.z);
    v.w = fmaf(v.w, a4.w, c4.w);
    *reinterpret_cast<float4*>(outnf + (size_t)n * 384 + f4 * 4) = v;
}

// ---------------- pooling ----------------

__device__ __forceinline__ int lbound(const int* __restrict__ b, int n, int v) {
    int lo = 0, hi = n;
    while (lo < hi) {
        int m = (lo + hi) >> 1;
        if (b[m] < v) lo = m + 1; else hi = m;
    }
    return lo;
}

__global__ void k_pool(const float* __restrict__ nf, const int* __restrict__ batch,
                       int N, float* __restrict__ out) {
    int g = blockIdx.x;
    int d = threadIdx.x;  // 384
    int lo = lbound(batch, N, g);
    int hi = lbound(batch, N, g + 1);
    float s = 0.f;
    for (int n = lo; n < hi; n++) s += nf[(size_t)n * 384 + d];
    out[(size_t)g * 384 + d] = s;
}

// ---------------- launch ----------------

extern "C" void kernel_launch(void* const* d_in, const int* in_sizes, int n_in,
                              void* d_out, int out_size, void* d_ws, size_t ws_size,
                              hipStream_t stream) {
    const float* x   = (const float*)d_in[0];
    const int*   ei  = (const int*)d_in[1];
    const int*   bat = (const int*)d_in[2];
    const float* sWl = (const float*)d_in[3];
    const float* sbl = (const float*)d_in[4];
    const float* sWr = (const float*)d_in[5];
    const float* gW1 = (const float*)d_in[6];
    const float* gb1 = (const float*)d_in[7];
    const float* gW2 = (const float*)d_in[8];
    const float* gb2 = (const float*)d_in[9];
    const float* bng = (const float*)d_in[10];
    const float* bnb = (const float*)d_in[11];

    const int N = in_sizes[0] / 128;
    const int E = in_sizes[1] / 2;
    const int G = out_size / 384 - N;
    const int* srcp = ei;
    const int* dstp = ei + E;

    // workspace carve (256B aligned)
    char* w = (char*)d_ws;
    auto alloc = [&](size_t bytes) -> void* {
        void* p = (void*)w;
        w += (bytes + 255) & ~(size_t)255;
        return p;
    };
    int*   rp     = (int*)alloc(((size_t)N + 1) * 4);
    int*   cursor = (int*)alloc((size_t)N * 4);       // deg counts -> positions
    int*   csr    = (int*)alloc((size_t)E * 4);
    int*   bsum   = (int*)alloc(4096);
    int*   bbase  = (int*)alloc(4096);
    float* gsum   = (float*)alloc(512);
    float* gsq    = (float*)alloc(512);               // contiguous with gsum
    float* abuf   = (float*)alloc(512);
    float* cbuf   = (float*)alloc(512);
    float* aggr   = (float*)alloc((size_t)N * 128 * 4);

    float* pooled = (float*)d_out;                    // [G][384]
    float* nf     = pooled + (size_t)G * 384;         // [N][384]

    const int nb = (N + 1023) / 1024;
    const int egrid = (E + 255) / 256;
    const int agrid = (N + 7) / 8;
    const int ggrid = (N + 63) / 64;
    const int ngrid = (N * 32 + 255) / 256;

    // ---- CSR build ----
    hipMemsetAsync(cursor, 0, (size_t)N * 4, stream);
    k_count<<<egrid, 256, 0, stream>>>(dstp, E, cursor);
    k_scan_a<<<nb, 256, 0, stream>>>(cursor, N, bsum);
    k_scan_b<<<1, 64, 0, stream>>>(bsum, nb, bbase);
    k_scan_c<<<nb, 256, 0, stream>>>(cursor, N, bbase, rp, E);
    k_fill<<<egrid, 256, 0, stream>>>(srcp, dstp, E, cursor, csr);

    // ---- Layer 0: SAGE ----
    k_aggr_sage<<<agrid, 256, 0, stream>>>(rp, csr, x, aggr, N);
    // unnormalized h -> nf slice 0 (stride 384)
    k_gemm<<<ggrid, 256, 0, stream>>>(aggr, 128, sWl, x, 128, sWr, sbl, nf, 384, N);
    hipMemsetAsync(gsum, 0, 1024, stream);
    k_stats<<<512, 256, 0, stream>>>(nf, 384, N, gsum, gsq);
    k_bnfin<<<1, 128, 0, stream>>>(gsum, gsq, bng, bnb, N, abuf, cbuf);
    k_norm<<<ngrid, 256, 0, stream>>>(nf, 384, abuf, cbuf, nf, N);

    // ---- Layers 1,2: GIN ----
    for (int l = 1; l < 3; l++) {
        const float* h = nf + (size_t)(l - 1) * 128;
        float* tslice = nf + (size_t)l * 128;
        const float* W1 = gW1 + (size_t)(l - 1) * 128 * 128;
        const float* W2 = gW2 + (size_t)(l - 1) * 128 * 128;
        const float* b1 = gb1 + (size_t)(l - 1) * 128;
        const float* b2 = gb2 + (size_t)(l - 1) * 128;

        k_aggr_gin<<<agrid, 256, 0, stream>>>(rp, csr, h, aggr, N);
        // t = relu((h+aggr)@W1 + b1) -> nf slice l (temp, stride 384)
        k_gemm<<<ggrid, 256, 0, stream>>>(aggr, 128, W1, nullptr, 0, nullptr, b1, tslice, 384, N);
        // u = relu(t@W2 + b2) -> aggr (stride 128)
        k_gemm<<<ggrid, 256, 0, stream>>>(tslice, 384, W2, nullptr, 0, nullptr, b2, aggr, 128, N);
        hipMemsetAsync(gsum, 0, 1024, stream);
        k_stats<<<512, 256, 0, stream>>>(aggr, 128, N, gsum, gsq);
        k_bnfin<<<1, 128, 0, stream>>>(gsum, gsq, bng + l * 128, bnb + l * 128, N, abuf, cbuf);
        k_norm<<<ngrid, 256, 0, stream>>>(aggr, 128, abuf, cbuf, tslice, N);
    }

    // ---- pooling ----
    k_pool<<<G, 384, 0, stream>>>(nf, bat, N, pooled);
}

// Round 3
// 1098.025 us; speedup vs baseline: 1.0611x; 1.0611x over previous
//
#include <hip/hip_runtime.h>
#include <hip/hip_bf16.h>

// ---------------------------------------------------------------------------
// GNN encoder: SAGEConv -> BN -> 2x (GINConv -> BN), concat outputs + add-pool
// N=100000, E=1600000, F=D=128, L=3, G=500
// Round 3: bf16 gather tables + MFMA GEMMs with hi/lo-split weights
// (W = W_hi + W_lo, 2 MFMAs per fragment) to kill the correlated W-rounding
// error that failed round 2. W fragments read from L2 (no LDS, no barrier).
// ---------------------------------------------------------------------------

#define BN_EPS 1e-5f

typedef short s8v __attribute__((ext_vector_type(8)));
typedef float f4v __attribute__((ext_vector_type(4)));

__device__ __forceinline__ float bflo(unsigned u) { return __uint_as_float(u << 16); }
__device__ __forceinline__ float bfhi(unsigned u) { return __uint_as_float(u & 0xffff0000u); }
__device__ __forceinline__ unsigned short f2bf(float f) {
    unsigned u = __float_as_uint(f);
    unsigned r = (u + 0x7fffu + ((u >> 16) & 1u)) >> 16;  // RTNE
    return (unsigned short)r;
}
__device__ __forceinline__ unsigned pk2(float a, float b) {
    return (unsigned)f2bf(a) | ((unsigned)f2bf(b) << 16);
}
__device__ __forceinline__ void unpack8(uint4 u, float* v) {
    v[0] = bflo(u.x); v[1] = bfhi(u.x);
    v[2] = bflo(u.y); v[3] = bfhi(u.y);
    v[4] = bflo(u.z); v[5] = bfhi(u.z);
    v[6] = bflo(u.w); v[7] = bfhi(u.w);
}

// ---------------- CSR build ----------------

__global__ void k_count(const int* __restrict__ dst, int E, int* __restrict__ cnt) {
    int e = blockIdx.x * 256 + threadIdx.x;
    if (e < E) atomicAdd(&cnt[dst[e]], 1);
}

__global__ void k_scan_a(const int* __restrict__ deg, int N, int* __restrict__ bsum) {
    __shared__ int sm[256];
    int base = blockIdx.x * 1024;
    int s = 0;
#pragma unroll
    for (int t = 0; t < 4; t++) {
        int i = base + threadIdx.x + t * 256;
        if (i < N) s += deg[i];
    }
    sm[threadIdx.x] = s;
    __syncthreads();
    for (int off = 128; off > 0; off >>= 1) {
        if (threadIdx.x < off) sm[threadIdx.x] += sm[threadIdx.x + off];
        __syncthreads();
    }
    if (threadIdx.x == 0) bsum[blockIdx.x] = sm[0];
}

__global__ void k_scan_b(const int* __restrict__ bsum, int nb, int* __restrict__ bbase) {
    if (threadIdx.x == 0) {
        int run = 0;
        for (int i = 0; i < nb; i++) { bbase[i] = run; run += bsum[i]; }
    }
}

__global__ void k_scan_c(int* __restrict__ deg_cursor, int N,
                         const int* __restrict__ bbase, int* __restrict__ rp, int E) {
    __shared__ int sm[256];
    int base = blockIdx.x * 1024 + threadIdx.x * 4;
    int v[4];
    int s = 0;
#pragma unroll
    for (int t = 0; t < 4; t++) {
        int i = base + t;
        v[t] = (i < N) ? deg_cursor[i] : 0;
        s += v[t];
    }
    sm[threadIdx.x] = s;
    __syncthreads();
    for (int off = 1; off < 256; off <<= 1) {
        int y = (threadIdx.x >= off) ? sm[threadIdx.x - off] : 0;
        __syncthreads();
        sm[threadIdx.x] += y;
        __syncthreads();
    }
    int excl = sm[threadIdx.x] - s;
    int b = bbase[blockIdx.x] + excl;
#pragma unroll
    for (int t = 0; t < 4; t++) {
        int i = base + t;
        if (i < N) { rp[i] = b; deg_cursor[i] = b; b += v[t]; }
    }
    if (blockIdx.x == 0 && threadIdx.x == 0) rp[N] = E;
}

__global__ void k_fill(const int* __restrict__ src, const int* __restrict__ dst, int E,
                       int* __restrict__ cursor, int* __restrict__ csr) {
    int e = blockIdx.x * 256 + threadIdx.x;
    if (e < E) {
        int pos = atomicAdd(&cursor[dst[e]], 1);
        csr[pos] = src[e];
    }
}

// ---------------- conversions / weight packing ----------------

// f32 -> bf16, 8 elems/thread
__global__ void k_cvt_bf16(const float* __restrict__ in, uint4* __restrict__ out, int n8) {
    int i = blockIdx.x * 256 + threadIdx.x;
    if (i >= n8) return;
    const float4* p = reinterpret_cast<const float4*>(in) + (size_t)i * 2;
    float4 a = p[0], b = p[1];
    uint4 o;
    o.x = pk2(a.x, a.y); o.y = pk2(a.z, a.w);
    o.z = pk2(b.x, b.y); o.w = pk2(b.z, b.w);
    out[i] = o;
}

// pack one 128x128 f32 W into MFMA A-operand (W^T) fragment layout, split into
// bf16 hi plane (+0) and bf16 lo-residual plane (+16384):
// plane[((k>>3)*128 + d)*8 + (k&7)]
__global__ void k_pack_w(const float* __restrict__ W, unsigned short* __restrict__ out) {
    int idx = blockIdx.x * 256 + threadIdx.x;  // 16384
    int k = idx >> 7, d = idx & 127;
    float w = W[idx];
    unsigned short h = f2bf(w);
    float hf = __uint_as_float((unsigned)h << 16);
    unsigned short l = f2bf(w - hf);
    int o = (((k >> 3) * 128) + d) * 8 + (k & 7);
    out[o] = h;
    out[16384 + o] = l;
}

// ---------------- aggregation (bf16 src rows, 16 lanes x 16B per node) -----

template <bool SELF, bool MEAN>
__global__ void k_aggr(const int* __restrict__ rp, const int* __restrict__ csr,
                       const uint4* __restrict__ src, uint4* __restrict__ out, int N) {
    int node = blockIdx.x * 16 + (threadIdx.x >> 4);
    if (node >= N) return;
    int c = threadIdx.x & 15;
    float acc[8];
    if (SELF) {
        unpack8(src[(size_t)node * 16 + c], acc);
    } else {
#pragma unroll
        for (int k = 0; k < 8; k++) acc[k] = 0.f;
    }
    int lo = rp[node], hi = rp[node + 1];
    for (int j = lo; j < hi; j++) {
        int sn = csr[j];
        float v[8];
        unpack8(src[(size_t)sn * 16 + c], v);
#pragma unroll
        for (int k = 0; k < 8; k++) acc[k] += v[k];
    }
    if (MEAN) {
        float inv = 1.0f / fmaxf((float)(hi - lo), 1.0f);
#pragma unroll
        for (int k = 0; k < 8; k++) acc[k] *= inv;
    }
    uint4 o;
    o.x = pk2(acc[0], acc[1]); o.y = pk2(acc[2], acc[3]);
    o.z = pk2(acc[4], acc[5]); o.w = pk2(acc[6], acc[7]);
    out[(size_t)node * 16 + c] = o;
}

// ---------------- MFMA GEMM ----------------
// C = relu( sum_t A_t @ (Whi_t + Wlo_t) + bias ), A_t: [N x 128] bf16 rows.
// Swapped operands: mfma(A_op = W^T frag, B_op = node frag) -> C^T frags,
// lane holds node = l16, d = df*16 + lg*4 + reg (4 contiguous d per lane).
// W fragments streamed from global (L2-resident, 64KB/term). No LDS.
// Block: 256 thr = 4 waves; wave = 32 nodes; block = 128 nodes. K=128/term.

template <int TERMS, bool F32OUT>
__global__ __launch_bounds__(256) void k_gemm_mfma(
    const uint4* __restrict__ A1, const uint4* __restrict__ A2,
    const uint4* __restrict__ Wfrag,  // TERMS * 2 * 2048 uint4: [term][hi,lo]
    const float* __restrict__ bias,
    float* __restrict__ outF,                 // if F32OUT: stride 384
    unsigned short* __restrict__ outB,        // else: compact bf16 [N][128]
    int N) {
    const int tid = threadIdx.x;
    const int lane = tid & 63, wid = tid >> 6;
    const int nbase = blockIdx.x * 128 + wid * 32;
    const int l16 = lane & 15, lg = lane >> 4;

    f4v acc[2][8];
#pragma unroll
    for (int nf = 0; nf < 2; nf++)
#pragma unroll
        for (int df = 0; df < 8; df++) {
            acc[nf][df][0] = 0.f; acc[nf][df][1] = 0.f;
            acc[nf][df][2] = 0.f; acc[nf][df][3] = 0.f;
        }

#pragma unroll
    for (int t = 0; t < TERMS; t++) {
        const uint4* A = t ? A2 : A1;
        const uint4* Whi = Wfrag + (size_t)t * 4096;
        const uint4* Wlo = Whi + 2048;
        // node (B-operand) fragments: lane reads 16B of its node's row
        uint4 bvec[2][4];
#pragma unroll
        for (int nf = 0; nf < 2; nf++) {
            const uint4* row = A + (size_t)(nbase + nf * 16 + l16) * 16;
#pragma unroll
            for (int ks = 0; ks < 4; ks++) bvec[nf][ks] = row[ks * 4 + lg];
        }
#pragma unroll
        for (int ks = 0; ks < 4; ks++) {
            s8v b0 = __builtin_bit_cast(s8v, bvec[0][ks]);
            s8v b1 = __builtin_bit_cast(s8v, bvec[1][ks]);
#pragma unroll
            for (int df = 0; df < 8; df++) {
                int wi = (ks * 4 + lg) * 128 + df * 16 + l16;
                s8v ah = __builtin_bit_cast(s8v, Whi[wi]);
                s8v al = __builtin_bit_cast(s8v, Wlo[wi]);
                acc[0][df] = __builtin_amdgcn_mfma_f32_16x16x32_bf16(ah, b0, acc[0][df], 0, 0, 0);
                acc[1][df] = __builtin_amdgcn_mfma_f32_16x16x32_bf16(ah, b1, acc[1][df], 0, 0, 0);
                acc[0][df] = __builtin_amdgcn_mfma_f32_16x16x32_bf16(al, b0, acc[0][df], 0, 0, 0);
                acc[1][df] = __builtin_amdgcn_mfma_f32_16x16x32_bf16(al, b1, acc[1][df], 0, 0, 0);
            }
        }
    }

#pragma unroll
    for (int nf = 0; nf < 2; nf++) {
        int n = nbase + nf * 16 + l16;
        if (n < N) {
#pragma unroll
            for (int df = 0; df < 8; df++) {
                int d0 = df * 16 + lg * 4;
                const float4 bb = *reinterpret_cast<const float4*>(bias + d0);
                float4 o;
                o.x = fmaxf(acc[nf][df][0] + bb.x, 0.f);
                o.y = fmaxf(acc[nf][df][1] + bb.y, 0.f);
                o.z = fmaxf(acc[nf][df][2] + bb.z, 0.f);
                o.w = fmaxf(acc[nf][df][3] + bb.w, 0.f);
                if (F32OUT) {
                    *reinterpret_cast<float4*>(outF + (size_t)n * 384 + d0) = o;
                } else {
                    uint2 p;
                    p.x = pk2(o.x, o.y);
                    p.y = pk2(o.z, o.w);
                    *reinterpret_cast<uint2*>(outB + (size_t)n * 128 + d0) = p;
                }
            }
        }
    }
}

// ---------------- BatchNorm ----------------

template <bool BF16>
__global__ __launch_bounds__(256) void k_stats2(const void* __restrict__ in, int ldin, int N,
                                                float* __restrict__ gsum, float* __restrict__ gsq) {
    __shared__ float ss[16][16][8];
    __shared__ float sq[16][16][8];
    int c = threadIdx.x & 15, r = threadIdx.x >> 4;
    float s[8], q[8];
#pragma unroll
    for (int k = 0; k < 8; k++) { s[k] = 0.f; q[k] = 0.f; }
    for (int n = blockIdx.x * 16 + r; n < N; n += gridDim.x * 16) {
        float v[8];
        if (BF16) {
            unpack8(reinterpret_cast<const uint4*>(in)[(size_t)n * 16 + c], v);
        } else {
            const float* p = (const float*)in + (size_t)n * ldin + c * 8;
            float4 x0 = *reinterpret_cast<const float4*>(p);
            float4 x1 = *reinterpret_cast<const float4*>(p + 4);
            v[0] = x0.x; v[1] = x0.y; v[2] = x0.z; v[3] = x0.w;
            v[4] = x1.x; v[5] = x1.y; v[6] = x1.z; v[7] = x1.w;
        }
#pragma unroll
        for (int k = 0; k < 8; k++) { s[k] += v[k]; q[k] = fmaf(v[k], v[k], q[k]); }
    }
#pragma unroll
    for (int k = 0; k < 8; k++) { ss[r][c][k] = s[k]; sq[r][c][k] = q[k]; }
    __syncthreads();
    for (int off = 8; off > 0; off >>= 1) {
        if (r < off) {
#pragma unroll
            for (int k = 0; k < 8; k++) {
                ss[r][c][k] += ss[r + off][c][k];
                sq[r][c][k] += sq[r + off][c][k];
            }
        }
        __syncthreads();
    }
    if (r == 0) {
#pragma unroll
        for (int k = 0; k < 8; k++) {
            unsafeAtomicAdd(&gsum[c * 8 + k], ss[0][c][k]);
            unsafeAtomicAdd(&gsq[c * 8 + k], sq[0][c][k]);
        }
    }
}

__global__ void k_bnfin(const float* __restrict__ gsum, const float* __restrict__ gsq,
                        const float* __restrict__ gamma, const float* __restrict__ beta,
                        int N, float* __restrict__ a, float* __restrict__ c) {
    int d = threadIdx.x;  // 128
    float invN = 1.0f / (float)N;
    float mu = gsum[d] * invN;
    float var = gsq[d] * invN - mu * mu;
    float rs = rsqrtf(var + BN_EPS);
    float aa = gamma[d] * rs;
    a[d] = aa;
    c[d] = beta[d] - mu * aa;
}

// normalize: outF[n*384+f] = v*a[f]+c[f] ; optional compact bf16 copy
template <bool BF16IN>
__global__ void k_norm2(const void* __restrict__ in, int ldin,
                        const float* __restrict__ sa, const float* __restrict__ sc,
                        float* __restrict__ outF, uint4* __restrict__ outB, int N) {
    int idx = blockIdx.x * 256 + threadIdx.x;
    if (idx >= N * 16) return;
    int n = idx >> 4, cc = idx & 15;
    float v[8];
    if (BF16IN) {
        unpack8(reinterpret_cast<const uint4*>(in)[(size_t)n * 16 + cc], v);
    } else {
        const float* p = (const float*)in + (size_t)n * ldin + cc * 8;
        float4 x0 = *reinterpret_cast<const float4*>(p);
        float4 x1 = *reinterpret_cast<const float4*>(p + 4);
        v[0] = x0.x; v[1] = x0.y; v[2] = x0.z; v[3] = x0.w;
        v[4] = x1.x; v[5] = x1.y; v[6] = x1.z; v[7] = x1.w;
    }
    const float4 a0 = *reinterpret_cast<const float4*>(sa + cc * 8);
    const float4 a1 = *reinterpret_cast<const float4*>(sa + cc * 8 + 4);
    const float4 c0 = *reinterpret_cast<const float4*>(sc + cc * 8);
    const float4 c1 = *reinterpret_cast<const float4*>(sc + cc * 8 + 4);
    float y[8];
    y[0] = fmaf(v[0], a0.x, c0.x); y[1] = fmaf(v[1], a0.y, c0.y);
    y[2] = fmaf(v[2], a0.z, c0.z); y[3] = fmaf(v[3], a0.w, c0.w);
    y[4] = fmaf(v[4], a1.x, c1.x); y[5] = fmaf(v[5], a1.y, c1.y);
    y[6] = fmaf(v[6], a1.z, c1.z); y[7] = fmaf(v[7], a1.w, c1.w);
    float* po = outF + (size_t)n * 384 + cc * 8;
    *reinterpret_cast<float4*>(po) = make_float4(y[0], y[1], y[2], y[3]);
    *reinterpret_cast<float4*>(po + 4) = make_float4(y[4], y[5], y[6], y[7]);
    if (outB) {
        uint4 o;
        o.x = pk2(y[0], y[1]); o.y = pk2(y[2], y[3]);
        o.z = pk2(y[4], y[5]); o.w = pk2(y[6], y[7]);
        outB[(size_t)n * 16 + cc] = o;
    }
}

// ---------------- pooling ----------------

__device__ __forceinline__ int lbound(const int* __restrict__ b, int n, int v) {
    int lo = 0, hi = n;
    while (lo < hi) {
        int m = (lo + hi) >> 1;
        if (b[m] < v) lo = m + 1; else hi = m;
    }
    return lo;
}

__global__ void k_pool(const float* __restrict__ nf, const int* __restrict__ batch,
                       int N, float* __restrict__ out) {
    int g = blockIdx.x;
    int d = threadIdx.x;  // 384
    int lo = lbound(batch, N, g);
    int hi = lbound(batch, N, g + 1);
    float s = 0.f;
    for (int n = lo; n < hi; n++) s += nf[(size_t)n * 384 + d];
    out[(size_t)g * 384 + d] = s;
}

// ---------------- launch ----------------

extern "C" void kernel_launch(void* const* d_in, const int* in_sizes, int n_in,
                              void* d_out, int out_size, void* d_ws, size_t ws_size,
                              hipStream_t stream) {
    const float* x   = (const float*)d_in[0];
    const int*   ei  = (const int*)d_in[1];
    const int*   bat = (const int*)d_in[2];
    const float* sWl = (const float*)d_in[3];
    const float* sbl = (const float*)d_in[4];
    const float* sWr = (const float*)d_in[5];
    const float* gW1 = (const float*)d_in[6];
    const float* gb1 = (const float*)d_in[7];
    const float* gW2 = (const float*)d_in[8];
    const float* gb2 = (const float*)d_in[9];
    const float* bng = (const float*)d_in[10];
    const float* bnb = (const float*)d_in[11];

    const int N = in_sizes[0] / 128;
    const int E = in_sizes[1] / 2;
    const int G = out_size / 384 - N;
    const int* srcp = ei;
    const int* dstp = ei + E;

    char* w = (char*)d_ws;
    auto alloc = [&](size_t bytes) -> void* {
        void* p = (void*)w;
        w += (bytes + 255) & ~(size_t)255;
        return p;
    };
    const size_t Npad = (size_t)(N + 128);
    int*   rp     = (int*)alloc(((size_t)N + 1) * 4);
    int*   cursor = (int*)alloc((size_t)N * 4);
    int*   csr    = (int*)alloc((size_t)E * 4);
    int*   bsum   = (int*)alloc(4096);
    int*   bbase  = (int*)alloc(4096);
    float* gsum   = (float*)alloc(512);
    float* gsq    = (float*)alloc(512);     // contiguous with gsum
    float* abuf   = (float*)alloc(512);
    float* cbuf   = (float*)alloc(512);
    // 6 weights x (hi plane + lo plane) x 16384 bf16
    unsigned short* Wp = (unsigned short*)alloc((size_t)6 * 2 * 16384 * 2);
    unsigned short* ab = (unsigned short*)alloc(Npad * 256);  // bf16 [N][128] (+pad)
    unsigned short* tb = (unsigned short*)alloc(Npad * 256);  // bf16 [N][128] (+pad)

    float* pooled = (float*)d_out;                 // [G][384]
    float* nf     = pooled + (size_t)G * 384;      // [N][384]

    const int nb     = (N + 1023) / 1024;
    const int egrid  = (E + 255) / 256;
    const int agrid  = (N + 15) / 16;
    const int ggrid  = (N + 127) / 128;
    const int vgrid  = (N * 16 + 255) / 256;

    // ---- CSR build ----
    hipMemsetAsync(cursor, 0, (size_t)N * 4, stream);
    k_count<<<egrid, 256, 0, stream>>>(dstp, E, cursor);
    k_scan_a<<<nb, 256, 0, stream>>>(cursor, N, bsum);
    k_scan_b<<<1, 64, 0, stream>>>(bsum, nb, bbase);
    k_scan_c<<<nb, 256, 0, stream>>>(cursor, N, bbase, rp, E);
    k_fill<<<egrid, 256, 0, stream>>>(srcp, dstp, E, cursor, csr);

    // ---- prep: x -> bf16 (in tb), pack weights (hi+lo planes) ----
    k_cvt_bf16<<<vgrid, 256, 0, stream>>>(x, (uint4*)tb, N * 16);
    k_pack_w<<<64, 256, 0, stream>>>(sWl,         Wp + 0 * 32768);
    k_pack_w<<<64, 256, 0, stream>>>(sWr,         Wp + 1 * 32768);
    k_pack_w<<<64, 256, 0, stream>>>(gW1,         Wp + 2 * 32768);
    k_pack_w<<<64, 256, 0, stream>>>(gW2,         Wp + 3 * 32768);
    k_pack_w<<<64, 256, 0, stream>>>(gW1 + 16384, Wp + 4 * 32768);
    k_pack_w<<<64, 256, 0, stream>>>(gW2 + 16384, Wp + 5 * 32768);

    // ---- Layer 0: SAGE ----
    k_aggr<false, true><<<agrid, 256, 0, stream>>>(rp, csr, (const uint4*)tb, (uint4*)ab, N);
    // h0(pre-BN, relu'd) = relu(aggr@Wl + bl + x@Wr) -> nf slice 0 (f32, stride 384)
    k_gemm_mfma<2, true><<<ggrid, 256, 0, stream>>>(
        (const uint4*)ab, (const uint4*)tb, (const uint4*)Wp, sbl, nf, nullptr, N);
    hipMemsetAsync(gsum, 0, 1024, stream);
    k_stats2<false><<<512, 256, 0, stream>>>(nf, 384, N, gsum, gsq);
    k_bnfin<<<1, 128, 0, stream>>>(gsum, gsq, bng, bnb, N, abuf, cbuf);
    // normalize in place + compact bf16 h0 -> tb
    k_norm2<false><<<vgrid, 256, 0, stream>>>(nf, 384, abuf, cbuf, nf, (uint4*)tb, N);

    // ---- Layers 1,2: GIN ----
    for (int l = 1; l < 3; l++) {
        const uint4* W1p = (const uint4*)(Wp + (size_t)(2 + (l - 1) * 2) * 32768);
        const uint4* W2p = (const uint4*)(Wp + (size_t)(3 + (l - 1) * 2) * 32768);
        const float* b1 = gb1 + (size_t)(l - 1) * 128;
        const float* b2 = gb2 + (size_t)(l - 1) * 128;

        // ab = h + sum_nb h  (gather from tb)
        k_aggr<true, false><<<agrid, 256, 0, stream>>>(rp, csr, (const uint4*)tb, (uint4*)ab, N);
        // t = relu(ab@W1 + b1) -> tb
        k_gemm_mfma<1, false><<<ggrid, 256, 0, stream>>>(
            (const uint4*)ab, nullptr, W1p, b1, nullptr, tb, N);
        // u = relu(t@W2 + b2) -> ab
        k_gemm_mfma<1, false><<<ggrid, 256, 0, stream>>>(
            (const uint4*)tb, nullptr, W2p, b2, nullptr, ab, N);
        hipMemsetAsync(gsum, 0, 1024, stream);
        k_stats2<true><<<512, 256, 0, stream>>>(ab, 128, N, gsum, gsq);
        k_bnfin<<<1, 128, 0, stream>>>(gsum, gsq, bng + l * 128, bnb + l * 128, N, abuf, cbuf);
        // normalize -> nf slice l (f32) + compact bf16 h_l -> tb (not needed after layer 2)
        k_norm2<true><<<vgrid, 256, 0, stream>>>(ab, 128, abuf, cbuf, nf + (size_t)l * 128,
                                                 (l < 2) ? (uint4*)tb : nullptr, N);
    }

    // ---- pooling ----
    k_pool<<<G, 384, 0, stream>>>(nf, bat, N, pooled);
}